// Round 17
// baseline (238.586 us; speedup 1.0000x reference)
//
#include <hip/hip_runtime.h>

// CNN encoder round 17 (= round 16 + conv_l12 occupancy fix):
//  - conv_l12 tile 32x16 -> 32x8 yT2 px: LDS 75KB -> 43.5KB => 3 blocks/CU
//    (24 waves/CU, was 8-ish). Grid 2048 -> 4096. Halo redundancy 1.72->2.06x
//    (+~9MB fetch) traded for ~2.2x occupancy on a latency-bound kernel.
//  - everything else unchanged from round 16.

typedef __attribute__((ext_vector_type(8))) short short8v;
typedef __attribute__((ext_vector_type(4))) float float4v;
typedef unsigned short u16;

#define LRELU_NEG 0.2f
#define BN_EPS 1e-5f

__device__ __forceinline__ float bf2f(u16 u){ union{unsigned i; float f;} v; v.i=(unsigned)u<<16; return v.f; }
__device__ __forceinline__ u16 f2bf(float f){ unsigned x=__float_as_uint(f); x += 0x7FFFu + ((x>>16)&1u); return (u16)(x>>16); }
__device__ __forceinline__ float lrelu(float v){ return v<0.f? LRELU_NEG*v : v; }
// packed f32x2 -> bf16x2 (RNE), low word = a
__device__ __forceinline__ unsigned pkbf(float a, float b) {
  unsigned r;
  asm("v_cvt_pk_bf16_f32 %0, %1, %2" : "=v"(r) : "v"(a), "v"(b));
  return r;
}

// ---------------------------------------------------------------------------
// prep_all: weight packing + bl2.
// ---------------------------------------------------------------------------
__device__ __forceinline__ void packw(int i, const float* __restrict__ w, u16* __restrict__ dst,
                                      int IC, int OC, int KSZ, int CPR) {
  int kq = i & 31, oc = (i>>5) % OC, c = i/(OC*32);
  int ky = c / CPR, r = c % CPR;
  int kk = r*32 + kq; int kx = kk / IC, ic = kk % IC;
  float v = (kx < KSZ) ? w[(((size_t)oc*IC + ic)*KSZ + ky)*KSZ + kx] : 0.f;
  dst[i] = f2bf(v);
}

__global__ __launch_bounds__(256) void prep_all(
    const float* __restrict__ w11, const float* __restrict__ w12,
    const float* __restrict__ b12, const float* __restrict__ cw,
    const float* __restrict__ wc1, const float* __restrict__ wc2,
    const float* __restrict__ wc3, const float* __restrict__ wc4,
    u16* __restrict__ wl1d, u16* __restrict__ wl2m, float* __restrict__ bl2,
    u16* __restrict__ d1, u16* __restrict__ d2, u16* __restrict__ d3, u16* __restrict__ d4) {
  int i = blockIdx.x*256 + threadIdx.x;
  if (i < 16) {
    bl2[i] = (i<8)? b12[i] : 0.f;
  } else if (i < 49168) {                        // wl1d [b][c6][row16][k32]
    int j = i - 16;
    int b = j / 3072, r = j % 3072;
    int c = r >> 9, r2 = r & 511;
    int row = r2 >> 5, kk = r2 & 31;
    int kx = kk >> 2, ic = kk & 3;
    int grp = row >> 3, oc = row & 7;
    int ky = c - grp;
    float v = 0.f;
    if (ic < 3 && kx < 5 && ky >= 0 && ky < 5)
      v = (oc < 4) ? w11[((oc*3+ic)*5+ky)*5+kx]
                   : cw[b*1900 + (oc-4)*75 + ic*25 + ky*5 + kx];
    wl1d[j] = f2bf(v);
  } else if (i < 131088) {                       // wl2m [b][c10][oc16][kq32]
    int j = i - 49168;
    int kq = j & 31, oc = (j>>5) & 15, c = (j>>9) % 10, b = j / 5120;
    int ky = c >> 1, r = c & 1;
    int kk = r*32 + kq; int kx = kk >> 3, ic = kk & 7;
    float v = 0.f;
    if (kx < 5)
      v = (oc < 8) ? w12[((oc*8+ic)*5+ky)*5+kx]
                   : cw[b*1900 + 300 + ((oc-8)*8+ic)*25 + ky*5 + kx];
    wl2m[j] = f2bf(v);
  } else if (i < 418832) {                       // shared-weight packs
    int j = i - 131088;
    if (j < 15360) packw(j, wc1, d1, 16, 32, 5, 3);
    else if (j < 66560) packw(j-15360, wc2, d2, 32, 64, 5, 5);
    else if (j < 140288) packw(j-66560, wc3, d3, 64, 128, 3, 6);
    else packw(j-140288, wc4, d4, 128, 128, 3, 12);
  }
}

// ---------------------------------------------------------------------------
// FUSED L1+L2. Block = one 32x8 yT2 tile (grid 256 x 16 batches, 512 thr).
// Phase 1: stage x [24 rows][88 cols][4ch] bf16 (origin 2x0-4, 2y0-4).
// Phase 2: L1 dual-row MFMA -> sh1 [20 rows][2][40][8].
// Phase 3: L2 MFMA from sh1 -> yT2 + partials.
// LDS ~43.5KB -> 3 blocks/CU.
// ---------------------------------------------------------------------------
__global__ __launch_bounds__(512) void conv_l12(const float* __restrict__ x,
    const u16* __restrict__ wl1d, const float* __restrict__ b11,
    const u16* __restrict__ wl2m, const float* __restrict__ bl2,
    u16* __restrict__ yT2, float2* __restrict__ part2) {
  __shared__ __align__(16) u16 sx[24*88*4];      // 16896 B
  __shared__ __align__(16) u16 sh1[20*2*40*8];   // 25600 B
  __shared__ float sred[8][16][2];

  const int tid = threadIdx.x, b = blockIdx.z;
  const int tx = blockIdx.x & 7, ty = blockIdx.x >> 3;
  const int x0 = tx*32, y0 = ty*8;
  const int xg0 = 2*x0 - 4, yg0 = 2*y0 - 4;

  // ---- phase 1: stage x ----
  const bool interior = (xg0 >= 0) & (xg0 + 87 < 512) & (yg0 >= 0) & (yg0 + 23 < 512);
  if (interior) {
    for (int e = tid; e < 528; e += 512) {       // 24 rows x 22 col-quads
      int row = e / 22, cg = e % 22;
      size_t base = ((size_t)b*3*512 + yg0 + row)*512 + xg0 + cg*4;
      float4v p0 = *(const float4v*)(x + base);
      float4v p1 = *(const float4v*)(x + base + 262144);
      float4v p2 = *(const float4v*)(x + base + 524288);
      uint4 lo, hi;
      lo.x = pkbf(p0[0], p1[0]); lo.y = pkbf(p2[0], 0.f);
      lo.z = pkbf(p0[1], p1[1]); lo.w = pkbf(p2[1], 0.f);
      hi.x = pkbf(p0[2], p1[2]); hi.y = pkbf(p2[2], 0.f);
      hi.z = pkbf(p0[3], p1[3]); hi.w = pkbf(p2[3], 0.f);
      u16* dp = sx + (row*88 + cg*4)*4;
      *(uint4*)dp = lo;
      *(uint4*)(dp + 8) = hi;
    }
  } else {
    for (int e = tid; e < 2112; e += 512) {      // 24 x 88 scalar units
      int row = e / 88, col = e % 88;
      int gy = yg0 + row, gx = xg0 + col;
      float v0 = 0.f, v1 = 0.f, v2 = 0.f;
      if (gy >= 0 && gy < 512 && gx >= 0 && gx < 512) {
        size_t base = ((size_t)b*3*512 + gy)*512 + gx;
        v0 = x[base]; v1 = x[base + 262144]; v2 = x[base + 524288];
      }
      uint2 pk2 = {pkbf(v0, v1), pkbf(v2, 0.f)};
      *(uint2*)(sx + e*4) = pk2;
    }
  }
  __syncthreads();

  const int lane = tid & 63, wid = tid >> 6;
  const int l15 = lane & 15, sub = lane >> 4;

  // ---- phase 2: L1 -> sh1 ----
  {
    short8v Wf[6];
    const u16* wb = wl1d + (size_t)b*3072;
#pragma unroll
    for (int c = 0; c < 6; c++)
      Wf[c] = *(const short8v*)(wb + (c*16 + l15)*32 + sub*8);
    float bvv[4];
#pragma unroll
    for (int r = 0; r < 4; r++) bvv[r] = (sub & 1) ? 0.f : b11[r];
    const int rsel = sub >> 1, ch0 = (sub & 1)*4;

    for (int t = wid; t < 50; t += 8) {          // 5 col-strips x 10 row-pairs
      int s = t % 5, p = t / 5;
      int colb = s*16 + l15;                     // local h1 col 0..79
      float4v acc = {0.f, 0.f, 0.f, 0.f};
#pragma unroll
      for (int c = 0; c < 6; c++) {
        const u16* ap = sx + (((2*p + c)*88 + colb) << 2) + sub*8;
        union { unsigned long long q[2]; short8v v; } ua;
        ua.q[0] = *(const unsigned long long*)(ap);
        ua.q[1] = *(const unsigned long long*)(ap + 4);
        acc = __builtin_amdgcn_mfma_f32_16x16x32_bf16(Wf[c], ua.v, acc, 0, 0, 0);
      }
      int r_l = 2*p + rsel;                      // local h1 row 0..19
      int hr = 2*y0 - 2 + r_l;
      int hc = 2*x0 - 2 + colb;
      bool valid = (hr >= 0) & (hr < 512) & (hc >= 0) & (hc < 512);
      float vr[4];
#pragma unroll
      for (int r = 0; r < 4; r++)
        vr[r] = valid ? lrelu(acc[r] + bvv[r]) : 0.f;
      unsigned long long q = (unsigned long long)pkbf(vr[0], vr[1])
                           | ((unsigned long long)pkbf(vr[2], vr[3]) << 32);
      *(unsigned long long*)(sh1 + ((r_l*2 + (colb & 1))*40 + (colb >> 1))*8 + ch0) = q;
    }
  }
  __syncthreads();

  // ---- phase 3: L2 from sh1 ----
  const u16* w2 = wl2m + (size_t)b*5120;
  float4v acc2[2];
  int oyl[2], oxl[2];
#pragma unroll
  for (int j = 0; j < 2; j++) {
    int t2 = wid*2 + j;                          // 0..15 D-tiles
    oyl[j] = t2 >> 1;                            // 0..7
    oxl[j] = (t2 & 1)*16;
    acc2[j] = (float4v){0.f, 0.f, 0.f, 0.f};
  }
#pragma unroll
  for (int c = 0; c < 10; c++) {
    int ky = c >> 1, r = c & 1;
    int kx = r*4 + sub;                          // 0..7 (kx>=5 weights are 0)
    short8v B = *(const short8v*)(w2 + ((size_t)c*16 + l15)*32 + sub*8);
#pragma unroll
    for (int j = 0; j < 2; j++) {
      int rowl = 2*oyl[j] + ky;                  // <= 18
      int pos = oxl[j] + l15 + (kx >> 1);        // <= 34
      short8v A = *(const short8v*)(sh1 + ((rowl*2 + (kx & 1))*40 + pos)*8);
      acc2[j] = __builtin_amdgcn_mfma_f32_16x16x32_bf16(A, B, acc2[j], 0, 0, 0);
    }
  }

  // ---- epilogue: yT2 parity store + BN partials ----
  float s_ = 0.f, q_ = 0.f;
  const float bv = bl2[l15];
#pragma unroll
  for (int j = 0; j < 2; j++) {
    const size_t rowb2 = ((size_t)b*260 + y0 + oyl[j] + 2)*2;
    const int oxs = x0 + oxl[j] + sub*4;
#pragma unroll
    for (int rr = 0; rr < 4; rr++) {
      float v = acc2[j][rr] + bv;
      int x_out = oxs + rr + 2;
      yT2[((rowb2 + (x_out & 1))*130 + (x_out >> 1))*16 + l15] = (u16)pkbf(v, 0.f);
      s_ += v; q_ += v*v;
    }
  }
  s_ += __shfl_xor(s_, 16); s_ += __shfl_xor(s_, 32);
  q_ += __shfl_xor(q_, 16); q_ += __shfl_xor(q_, 32);
  if (sub == 0) { sred[wid][l15][0] = s_; sred[wid][l15][1] = q_; }
  __syncthreads();
  if (tid < 16) {
    float S_ = 0.f, Q_ = 0.f;
#pragma unroll
    for (int w2i = 0; w2i < 8; w2i++) { S_ += sred[w2i][tid][0]; Q_ += sred[w2i][tid][1]; }
    part2[(size_t)tid*4096 + b*256 + blockIdx.x] = make_float2(S_, Q_);
  }
}

// ---------------------------------------------------------------------------
// Implicit-GEMM MFMA conv over PARITY-SPLIT padded NHWC input (round-10 form).
// ---------------------------------------------------------------------------
#define LOADC(cc, Ax, Bx) do {                                                   \
    const int ky_ = (cc) / CPR, r_ = (cc) % CPR;                                 \
    const int kk0_ = r_*32 + sub*8;                                              \
    const int kx_ = kk0_ / IC, ico_ = kk0_ % IC;                                 \
    const int t_ = kx_ + PADOFF;                                                 \
    _Pragma("unroll") for (int n_ = 0; n_ < WN; n_++)                            \
      Bx[n_] = *(const short8v*)(wbase + ((size_t)(cc)*OC + oc0 + n_*16 + l15)*32 + sub*8); \
    _Pragma("unroll") for (int f_ = 0; f_ < WM; f_++) {                          \
      int iy_ = 2*oyf[f_] + ky_ + PADOFF;                                        \
      Ax[f_] = *(const short8v*)(inb + (((size_t)iy_*2 + (t_&1))*IPWH + axb[f_] + (t_>>1))*IC + ico_); \
    }                                                                            \
  } while(0)

#define MFMAC(Ax, Bx) do {                                                       \
    _Pragma("unroll") for (int f_ = 0; f_ < WM; f_++)                            \
      _Pragma("unroll") for (int n_ = 0; n_ < WN; n_++)                          \
        acc[f_][n_] = __builtin_amdgcn_mfma_f32_16x16x32_bf16(Ax[f_], Bx[n_], acc[f_][n_], 0, 0, 0); \
  } while(0)

template <int IC, int OC, int KSZ, int S, int P, int CPR, int NCH,
          int IPH, int IPW, int OWL, int OPH, int OPW,
          int WM, int WN, int WVM, int WVN, bool PERS>
__global__ __launch_bounds__(WVM*WVN*64) void conv_mfma(
    const u16* __restrict__ in, const u16* __restrict__ wmfma,
    const float* __restrict__ bias, u16* __restrict__ out,
    float2* __restrict__ part2) {
  constexpr int OW = 1 << OWL;
  constexpr int PADOFF = 2 - P;
  constexpr int IPWH = IPW / 2;
  constexpr int OPWH = OPW / 2;
  const int tid = threadIdx.x, lane = tid & 63;
  const int w = tid >> 6, wm = w % WVM, wn = w / WVM;
  const int l15 = lane & 15, sub = lane >> 4;
  const int b = blockIdx.z;
  const int px0 = blockIdx.x * (16*WM*WVM) + wm * (16*WM);
  const int oc0 = blockIdx.y * (16*WN*WVN) + wn * (16*WN);

  int oyf[WM], oxb[WM], axb[WM];
#pragma unroll
  for (int f = 0; f < WM; f++) {
    int p = px0 + f*16;
    oyf[f] = p >> OWL;
    oxb[f] = p & (OW-1);
    axb[f] = oxb[f] + l15;
  }
  const u16* inb = in + (size_t)b*IPH*IPW*IC;
  const u16* wbase = wmfma + (PERS ? (size_t)b*NCH*OC*32 : (size_t)0);

  float4v acc[WM][WN];
#pragma unroll
  for (int f = 0; f < WM; f++)
#pragma unroll
    for (int n = 0; n < WN; n++) acc[f][n] = (float4v){0.f,0.f,0.f,0.f};

  constexpr int NC = KSZ * CPR;
  short8v A0[WM], B0[WN], A1[WM], B1[WN];
  LOADC(0, A0, B0);
#pragma unroll
  for (int c = 0; c < NC; c += 2) {
    if (c + 1 < NC) LOADC(c + 1, A1, B1);
    MFMAC(A0, B0);
    if (c + 2 < NC) LOADC(c + 2, A0, B0);
    if (c + 1 < NC) MFMAC(A1, B1);
  }

  // epilogue: +bias, store bf16 interior (parity layout), BN partials
  float s[WN], q[WN];
#pragma unroll
  for (int n = 0; n < WN; n++) { s[n] = 0.f; q[n] = 0.f; }
#pragma unroll
  for (int f = 0; f < WM; f++) {
    const int oxs = oxb[f] + sub*4;
    const size_t rowb2 = ((size_t)b*OPH + oyf[f] + 2)*2;
#pragma unroll
    for (int n = 0; n < WN; n++) {
      int oc = oc0 + n*16 + l15;
      float bv = bias[oc];
#pragma unroll
      for (int rr = 0; rr < 4; rr++) {
        float v = acc[f][n][rr] + bv;
        int x_out = oxs + rr + 2;
        out[((rowb2 + (x_out & 1))*OPWH + (x_out >> 1))*OC + oc] = f2bf(v);
        s[n] += v; q[n] += v*v;
      }
    }
  }
#pragma unroll
  for (int n = 0; n < WN; n++) {
    s[n] += __shfl_xor(s[n], 16); s[n] += __shfl_xor(s[n], 32);
    q[n] += __shfl_xor(q[n], 16); q[n] += __shfl_xor(q[n], 32);
  }
  __shared__ float sred[WVM*WVN][WN][16][2];
  if (sub == 0) {
#pragma unroll
    for (int n = 0; n < WN; n++) { sred[w][n][l15][0] = s[n]; sred[w][n][l15][1] = q[n]; }
  }
  __syncthreads();
  const int NBp = gridDim.x * gridDim.z;
  const int pb = blockIdx.z * gridDim.x + blockIdx.x;
  const int tot = WVN*WN*16;
  if (tid < tot) {
    int c16 = tid & 15, n = (tid >> 4) % WN, wn2 = tid / (16*WN);
    float S_ = 0.f, Q_ = 0.f;
    for (int wm2 = 0; wm2 < WVM; wm2++) {
      S_ += sred[wn2*WVM + wm2][n][c16][0];
      Q_ += sred[wn2*WVM + wm2][n][c16][1];
    }
    int c = blockIdx.y*(16*WN*WVN) + wn2*(16*WN) + n*16 + c16;
    part2[(size_t)c*NBp + pb] = make_float2(S_, Q_);
  }
}

// ---------------------------------------------------------------------------
// BN stage2: reduce per-block partials -> (scale, shift)
// ---------------------------------------------------------------------------
__global__ void bn_stage2(const float2* __restrict__ part2, const float* __restrict__ g,
                          const float* __restrict__ bb, float* __restrict__ stats,
                          int NBp, float invN) {
  int c = blockIdx.x;
  float s = 0.f, q = 0.f;
  for (int i = threadIdx.x; i < NBp; i += 64) {
    float2 p = part2[(size_t)c*NBp + i];
    s += p.x; q += p.y;
  }
  for (int o = 32; o > 0; o >>= 1) { s += __shfl_down(s, o); q += __shfl_down(q, o); }
  if (threadIdx.x == 0) {
    float m = s * invN;
    float var = q * invN - m*m;
    float sc = g[c] * rsqrtf(var + BN_EPS);
    stats[2*c] = sc;
    stats[2*c+1] = bb[c] - m*sc;
  }
}

// bn finalize in place over PARITY-SPLIT padded buffer.
template <int C, int PH, int PW, int HH, int WW>
__global__ __launch_bounds__(256) void bn_fin(u16* __restrict__ y, const float* __restrict__ stats,
                                              int total8) {
  int i = blockIdx.x*256 + threadIdx.x;
  if (i >= total8) return;
  size_t e = (size_t)i*8;
  int c0 = (int)(e & (C-1));
  int px = (int)(e / C);
  int xp = px % (PW/2);
  int t2 = px / (PW/2);
  int yy = (t2 >> 1) % PH;
  bool interior = (yy >= 2) & (yy < 2+HH) & (xp >= 1) & (xp <= WW/2);
  short8v u = *(short8v*)(y + e);
  short8v o;
#pragma unroll
  for (int j = 0; j < 8; j++) {
    float v = bf2f((u16)u[j]) * stats[2*(c0+j)] + stats[2*(c0+j)+1];
    o[j] = interior ? (short)f2bf(lrelu(v)) : (short)0;
  }
  *(short8v*)(y + e) = o;
}

// final: lrelu(bn(y6pad interior)) parity NHWC bf16 -> NCHW fp32 d_out
__global__ __launch_bounds__(256) void out_k(const u16* __restrict__ y6,
                                             const float* __restrict__ stats,
                                             float* __restrict__ out) {
  int i = blockIdx.x*256 + threadIdx.x;
  if (i >= 131072) return;
  size_t e = (size_t)i*4;
  int c0 = (int)(e & 127);
  int px = (int)(e >> 7);
  int loc = px & 255, b = px >> 8;
  int y = loc >> 4, x = loc & 15;
  int xi = x + 2;
  const u16* src = y6 + ((((size_t)b*20 + y + 2)*2 + (xi & 1))*10 + (xi >> 1))*128 + c0;
  ushort4 u = *(const ushort4*)src;
  float vv[4] = {bf2f(u.x), bf2f(u.y), bf2f(u.z), bf2f(u.w)};
#pragma unroll
  for (int j = 0; j < 4; j++) {
    int c = c0 + j;
    float v = vv[j] * stats[2*c] + stats[2*c+1];
    out[(((size_t)b*128 + c) << 8) + loc] = lrelu(v);
  }
}

// ---------------------------------------------------------------------------
extern "C" void kernel_launch(void* const* d_in, const int* in_sizes, int n_in,
                              void* d_out, int out_size, void* d_ws, size_t ws_size,
                              hipStream_t stream) {
  const float* x    = (const float*)d_in[0];
  const float* cw   = (const float*)d_in[1];
  const float* w11  = (const float*)d_in[2];
  const float* b11  = (const float*)d_in[3];
  const float* w12  = (const float*)d_in[4];
  const float* b12  = (const float*)d_in[5];
  const float* bn1g = (const float*)d_in[6];
  const float* bn1b = (const float*)d_in[7];
  const float* c2w[4] = {(const float*)d_in[8], (const float*)d_in[12],
                         (const float*)d_in[16], (const float*)d_in[20]};
  const float* c2b[4] = {(const float*)d_in[9], (const float*)d_in[13],
                         (const float*)d_in[17], (const float*)d_in[21]};
  const float* bng[4] = {(const float*)d_in[10], (const float*)d_in[14],
                         (const float*)d_in[18], (const float*)d_in[22]};
  const float* bnb[4] = {(const float*)d_in[11], (const float*)d_in[15],
                         (const float*)d_in[19], (const float*)d_in[23]};

  char* ws = (char*)d_ws;
  u16* y3   = (u16*)(ws);                          // 16x132x2x66x32 = 17,842,176
  u16* y4   = (u16*)(ws + 17842176);               // 16x68x2x34x64  =  9,469,952
  u16* y5   = (u16*)(ws + 27312128);               // 16x36x2x18x128 =  5,308,416
  u16* y6   = (u16*)(ws + 32620544);               // 16x20x2x10x128 =  1,638,400
  u16* yT2  = (u16*)(ws + 68158464);               // 16x260x2x130x16 = 34,611,200
  u16* wl2m = (u16*)(ws + 102769664);              // 163,840
  float* bl2    = (float*)(ws + 102933504);        // 64
  float2* part2 = (float2*)(ws + 102933568);       // 524,288 (16ch x 4096 blk)
  float* stats2 = (float*)(ws + 103457856);
  float* stats3 = stats2 + 32;
  float* stats4 = stats3 + 64;
  float* stats5 = stats4 + 128;
  float* stats6 = stats5 + 256;
  u16* wl1d = (u16*)(ws + 103460800);              // 98,304
  u16* wS1  = (u16*)(ws + 103559104);              // 30,720
  u16* wS2  = (u16*)(ws + 103589824);              // 102,400
  u16* wS3  = (u16*)(ws + 103692224);              // 147,456
  u16* wS4  = (u16*)(ws + 103839680);              // 294,912 -> ends 104,134,592

  prep_all<<<1637, 256, 0, stream>>>(w11, w12, b12, cw,
                                     c2w[0], c2w[1], c2w[2], c2w[3],
                                     wl1d, wl2m, bl2, wS1, wS2, wS3, wS4);

  // FUSED L1+L2: x -> yT2pad (pre-BN) + partials. h1 never touches HBM.
  conv_l12<<<dim3(256, 1, 16), 512, 0, stream>>>(x, wl1d, b11, wl2m, bl2, yT2, part2);

  bn_stage2<<<16, 64, 0, stream>>>(part2, bn1g, bn1b, stats2, 4096, 1.f/1048576.f);
  bn_fin<16,260,260,256,256><<<8450, 256, 0, stream>>>(yT2, stats2, 2163200);

  // S1: 16->32 k5 s2 -> y3pad
  conv_mfma<16,32,5,2,2, 3,15, 260,260, 7, 132,132, 2,2,4,1, false>
      <<<dim3(128,1,16), 256, 0, stream>>>(yT2, wS1, c2b[0], y3, part2);
  bn_stage2<<<32, 64, 0, stream>>>(part2, bng[0], bnb[0], stats3, 2048, 1.f/262144.f);
  bn_fin<32,132,132,128,128><<<4356, 256, 0, stream>>>(y3, stats3, 1115136);

  // S2: 32->64 k5 s2 -> y4pad
  conv_mfma<32,64,5,2,2, 5,25, 132,132, 6, 68,68, 2,2,2,2, false>
      <<<dim3(64,1,16), 256, 0, stream>>>(y3, wS2, c2b[1], y4, part2);
  bn_stage2<<<64, 64, 0, stream>>>(part2, bng[1], bnb[1], stats4, 1024, 1.f/65536.f);
  bn_fin<64,68,68,64,64><<<2312, 256, 0, stream>>>(y4, stats4, 591872);

  // S3: 64->128 k3 s2 -> y5pad
  conv_mfma<64,128,3,2,1, 6,18, 68,68, 5, 36,36, 2,2,2,2, false>
      <<<dim3(16,2,16), 256, 0, stream>>>(y4, wS3, c2b[2], y5, part2);
  bn_stage2<<<128, 64, 0, stream>>>(part2, bng[2], bnb[2], stats5, 256, 1.f/16384.f);
  bn_fin<128,36,36,32,32><<<1296, 256, 0, stream>>>(y5, stats5, 331776);

  // S4: 128->128 k3 s2 -> y6pad (pre-BN)
  conv_mfma<128,128,3,2,1, 12,36, 36,36, 4, 20,20, 2,2,1,2, false>
      <<<dim3(8,2,16), 128, 0, stream>>>(y5, wS4, c2b[3], y6, part2);
  bn_stage2<<<128, 64, 0, stream>>>(part2, bng[3], bnb[3], stats6, 128, 1.f/4096.f);

  out_k<<<512, 256, 0, stream>>>(y6, stats6, (float*)d_out);
}

// Round 18
// 223.603 us; speedup vs baseline: 1.0670x; 1.0670x over previous
//
#include <hip/hip_runtime.h>

// CNN encoder round 18 (= round 16 + phase-2 row-pair reuse):
//  - REVERT round-17 small tile (occupancy 34->51% was perf-neutral-negative:
//    not latency-bound). conv_l12 back to 32x16 tile, grid 128x16.
//  - conv_l12 phase 2: one thread computes tiles p,p+1 together; their 6-row
//    windows overlap 4 rows -> 8 LDS row reads serve 12 MFMAs (was 12 reads).
//    Cuts phase-2 LDS read traffic 33% (the modeled co-limiter with VALU).

typedef __attribute__((ext_vector_type(8))) short short8v;
typedef __attribute__((ext_vector_type(4))) float float4v;
typedef unsigned short u16;

#define LRELU_NEG 0.2f
#define BN_EPS 1e-5f

__device__ __forceinline__ float bf2f(u16 u){ union{unsigned i; float f;} v; v.i=(unsigned)u<<16; return v.f; }
__device__ __forceinline__ u16 f2bf(float f){ unsigned x=__float_as_uint(f); x += 0x7FFFu + ((x>>16)&1u); return (u16)(x>>16); }
__device__ __forceinline__ float lrelu(float v){ return v<0.f? LRELU_NEG*v : v; }
// packed f32x2 -> bf16x2 (RNE), low word = a
__device__ __forceinline__ unsigned pkbf(float a, float b) {
  unsigned r;
  asm("v_cvt_pk_bf16_f32 %0, %1, %2" : "=v"(r) : "v"(a), "v"(b));
  return r;
}

// ---------------------------------------------------------------------------
// prep_all: weight packing + bl2.
// ---------------------------------------------------------------------------
__device__ __forceinline__ void packw(int i, const float* __restrict__ w, u16* __restrict__ dst,
                                      int IC, int OC, int KSZ, int CPR) {
  int kq = i & 31, oc = (i>>5) % OC, c = i/(OC*32);
  int ky = c / CPR, r = c % CPR;
  int kk = r*32 + kq; int kx = kk / IC, ic = kk % IC;
  float v = (kx < KSZ) ? w[(((size_t)oc*IC + ic)*KSZ + ky)*KSZ + kx] : 0.f;
  dst[i] = f2bf(v);
}

__global__ __launch_bounds__(256) void prep_all(
    const float* __restrict__ w11, const float* __restrict__ w12,
    const float* __restrict__ b12, const float* __restrict__ cw,
    const float* __restrict__ wc1, const float* __restrict__ wc2,
    const float* __restrict__ wc3, const float* __restrict__ wc4,
    u16* __restrict__ wl1d, u16* __restrict__ wl2m, float* __restrict__ bl2,
    u16* __restrict__ d1, u16* __restrict__ d2, u16* __restrict__ d3, u16* __restrict__ d4) {
  int i = blockIdx.x*256 + threadIdx.x;
  if (i < 16) {
    bl2[i] = (i<8)? b12[i] : 0.f;
  } else if (i < 49168) {                        // wl1d [b][c6][row16][k32]
    int j = i - 16;
    int b = j / 3072, r = j % 3072;
    int c = r >> 9, r2 = r & 511;
    int row = r2 >> 5, kk = r2 & 31;
    int kx = kk >> 2, ic = kk & 3;
    int grp = row >> 3, oc = row & 7;
    int ky = c - grp;
    float v = 0.f;
    if (ic < 3 && kx < 5 && ky >= 0 && ky < 5)
      v = (oc < 4) ? w11[((oc*3+ic)*5+ky)*5+kx]
                   : cw[b*1900 + (oc-4)*75 + ic*25 + ky*5 + kx];
    wl1d[j] = f2bf(v);
  } else if (i < 131088) {                       // wl2m [b][c10][oc16][kq32]
    int j = i - 49168;
    int kq = j & 31, oc = (j>>5) & 15, c = (j>>9) % 10, b = j / 5120;
    int ky = c >> 1, r = c & 1;
    int kk = r*32 + kq; int kx = kk >> 3, ic = kk & 7;
    float v = 0.f;
    if (kx < 5)
      v = (oc < 8) ? w12[((oc*8+ic)*5+ky)*5+kx]
                   : cw[b*1900 + 300 + ((oc-8)*8+ic)*25 + ky*5 + kx];
    wl2m[j] = f2bf(v);
  } else if (i < 418832) {                       // shared-weight packs
    int j = i - 131088;
    if (j < 15360) packw(j, wc1, d1, 16, 32, 5, 3);
    else if (j < 66560) packw(j-15360, wc2, d2, 32, 64, 5, 5);
    else if (j < 140288) packw(j-66560, wc3, d3, 64, 128, 3, 6);
    else packw(j-140288, wc4, d4, 128, 128, 3, 12);
  }
}

// ---------------------------------------------------------------------------
// FUSED L1+L2. Block = one 32x16 yT2 tile (grid 128 x 16 batches, 512 thr).
// Phase 1: stage x [40 rows][88 cols][4ch] bf16.
// Phase 2: L1 dual-row MFMA, ROW-PAIR tiles (p,p+1 share 4 of 6 input rows)
//          -> sh1 [36 rows][2][40][8].
// Phase 3: L2 MFMA from sh1 -> yT2 + partials.
// ---------------------------------------------------------------------------
__global__ __launch_bounds__(512) void conv_l12(const float* __restrict__ x,
    const u16* __restrict__ wl1d, const float* __restrict__ b11,
    const u16* __restrict__ wl2m, const float* __restrict__ bl2,
    u16* __restrict__ yT2, float2* __restrict__ part2) {
  __shared__ __align__(16) u16 sx[40*88*4];      // 28160 B
  __shared__ __align__(16) u16 sh1[36*2*40*8];   // 46080 B
  __shared__ float sred[8][16][2];

  const int tid = threadIdx.x, b = blockIdx.z;
  const int tx = blockIdx.x & 7, ty = blockIdx.x >> 3;
  const int x0 = tx*32, y0 = ty*16;
  const int xg0 = 2*x0 - 4, yg0 = 2*y0 - 4;

  // ---- phase 1: stage x ----
  const bool interior = (xg0 >= 0) & (xg0 + 87 < 512) & (yg0 >= 0) & (yg0 + 39 < 512);
  if (interior) {
    for (int e = tid; e < 880; e += 512) {
      int row = e / 22, cg = e % 22;
      size_t base = ((size_t)b*3*512 + yg0 + row)*512 + xg0 + cg*4;
      float4v p0 = *(const float4v*)(x + base);
      float4v p1 = *(const float4v*)(x + base + 262144);
      float4v p2 = *(const float4v*)(x + base + 524288);
      uint4 lo, hi;
      lo.x = pkbf(p0[0], p1[0]); lo.y = pkbf(p2[0], 0.f);
      lo.z = pkbf(p0[1], p1[1]); lo.w = pkbf(p2[1], 0.f);
      hi.x = pkbf(p0[2], p1[2]); hi.y = pkbf(p2[2], 0.f);
      hi.z = pkbf(p0[3], p1[3]); hi.w = pkbf(p2[3], 0.f);
      u16* dp = sx + (row*88 + cg*4)*4;
      *(uint4*)dp = lo;
      *(uint4*)(dp + 8) = hi;
    }
  } else {
    for (int e = tid; e < 3520; e += 512) {
      int row = e / 88, col = e % 88;
      int gy = yg0 + row, gx = xg0 + col;
      float v0 = 0.f, v1 = 0.f, v2 = 0.f;
      if (gy >= 0 && gy < 512 && gx >= 0 && gx < 512) {
        size_t base = ((size_t)b*3*512 + gy)*512 + gx;
        v0 = x[base]; v1 = x[base + 262144]; v2 = x[base + 524288];
      }
      uint2 pk2 = {pkbf(v0, v1), pkbf(v2, 0.f)};
      *(uint2*)(sx + e*4) = pk2;
    }
  }
  __syncthreads();

  const int lane = tid & 63, wid = tid >> 6;
  const int l15 = lane & 15, sub = lane >> 4;

  // ---- phase 2: L1 -> sh1 (row-pair tiles) ----
  {
    short8v Wf[6];
    const u16* wb = wl1d + (size_t)b*3072;
#pragma unroll
    for (int c = 0; c < 6; c++)
      Wf[c] = *(const short8v*)(wb + (c*16 + l15)*32 + sub*8);
    float bvv[4];
#pragma unroll
    for (int r = 0; r < 4; r++) bvv[r] = (sub & 1) ? 0.f : b11[r];
    const int rsel = sub >> 1, ch0 = (sub & 1)*4;

    for (int t = wid; t < 45; t += 8) {          // 5 col-strips x 9 p-pairs
      int s = t % 5, pp = t / 5;
      int colb = s*16 + l15;                     // local h1 col 0..79
      short8v Af[8];
#pragma unroll
      for (int c = 0; c < 8; c++) {
        const u16* ap = sx + (((4*pp + c)*88 + colb) << 2) + sub*8;
        union { unsigned long long q[2]; short8v v; } ua;
        ua.q[0] = *(const unsigned long long*)(ap);
        ua.q[1] = *(const unsigned long long*)(ap + 4);
        Af[c] = ua.v;
      }
      float4v a0 = {0.f,0.f,0.f,0.f}, a1 = {0.f,0.f,0.f,0.f};
#pragma unroll
      for (int c = 0; c < 6; c++) {
        a0 = __builtin_amdgcn_mfma_f32_16x16x32_bf16(Wf[c], Af[c],   a0, 0, 0, 0);
        a1 = __builtin_amdgcn_mfma_f32_16x16x32_bf16(Wf[c], Af[c+2], a1, 0, 0, 0);
      }
      const int hc = 2*x0 - 2 + colb;
#pragma unroll
      for (int half = 0; half < 2; half++) {
        int r_l = 4*pp + 2*half + rsel;          // local h1 row 0..35
        int hr = 2*y0 - 2 + r_l;
        bool valid = (hr >= 0) & (hr < 512) & (hc >= 0) & (hc < 512);
        float4v& ac = half ? a1 : a0;
        float vr[4];
#pragma unroll
        for (int r = 0; r < 4; r++)
          vr[r] = valid ? lrelu(ac[r] + bvv[r]) : 0.f;
        unsigned long long q = (unsigned long long)pkbf(vr[0], vr[1])
                             | ((unsigned long long)pkbf(vr[2], vr[3]) << 32);
        *(unsigned long long*)(sh1 + ((r_l*2 + (colb & 1))*40 + (colb >> 1))*8 + ch0) = q;
      }
    }
  }
  __syncthreads();

  // ---- phase 3: L2 from sh1 ----
  const u16* w2 = wl2m + (size_t)b*5120;
  float4v acc2[4];
  int oyl[4], oxl[4];
#pragma unroll
  for (int j = 0; j < 4; j++) {
    int t2 = wid*4 + j;
    oyl[j] = t2 >> 1;
    oxl[j] = (t2 & 1)*16;
    acc2[j] = (float4v){0.f, 0.f, 0.f, 0.f};
  }
#pragma unroll
  for (int c = 0; c < 10; c++) {
    int ky = c >> 1, r = c & 1;
    int kx = r*4 + sub;
    short8v B = *(const short8v*)(w2 + ((size_t)c*16 + l15)*32 + sub*8);
#pragma unroll
    for (int j = 0; j < 4; j++) {
      int rowl = 2*oyl[j] + ky;
      int pos = oxl[j] + l15 + (kx >> 1);
      short8v A = *(const short8v*)(sh1 + ((rowl*2 + (kx & 1))*40 + pos)*8);
      acc2[j] = __builtin_amdgcn_mfma_f32_16x16x32_bf16(A, B, acc2[j], 0, 0, 0);
    }
  }

  // ---- epilogue: yT2 parity store + BN partials ----
  float s_ = 0.f, q_ = 0.f;
  const float bv = bl2[l15];
#pragma unroll
  for (int j = 0; j < 4; j++) {
    const size_t rowb2 = ((size_t)b*260 + y0 + oyl[j] + 2)*2;
    const int oxs = x0 + oxl[j] + sub*4;
#pragma unroll
    for (int rr = 0; rr < 4; rr++) {
      float v = acc2[j][rr] + bv;
      int x_out = oxs + rr + 2;
      yT2[((rowb2 + (x_out & 1))*130 + (x_out >> 1))*16 + l15] = (u16)pkbf(v, 0.f);
      s_ += v; q_ += v*v;
    }
  }
  s_ += __shfl_xor(s_, 16); s_ += __shfl_xor(s_, 32);
  q_ += __shfl_xor(q_, 16); q_ += __shfl_xor(q_, 32);
  if (sub == 0) { sred[wid][l15][0] = s_; sred[wid][l15][1] = q_; }
  __syncthreads();
  if (tid < 16) {
    float S_ = 0.f, Q_ = 0.f;
#pragma unroll
    for (int w2i = 0; w2i < 8; w2i++) { S_ += sred[w2i][tid][0]; Q_ += sred[w2i][tid][1]; }
    part2[(size_t)tid*2048 + b*128 + blockIdx.x] = make_float2(S_, Q_);
  }
}

// ---------------------------------------------------------------------------
// Implicit-GEMM MFMA conv over PARITY-SPLIT padded NHWC input (round-10 form).
// ---------------------------------------------------------------------------
#define LOADC(cc, Ax, Bx) do {                                                   \
    const int ky_ = (cc) / CPR, r_ = (cc) % CPR;                                 \
    const int kk0_ = r_*32 + sub*8;                                              \
    const int kx_ = kk0_ / IC, ico_ = kk0_ % IC;                                 \
    const int t_ = kx_ + PADOFF;                                                 \
    _Pragma("unroll") for (int n_ = 0; n_ < WN; n_++)                            \
      Bx[n_] = *(const short8v*)(wbase + ((size_t)(cc)*OC + oc0 + n_*16 + l15)*32 + sub*8); \
    _Pragma("unroll") for (int f_ = 0; f_ < WM; f_++) {                          \
      int iy_ = 2*oyf[f_] + ky_ + PADOFF;                                        \
      Ax[f_] = *(const short8v*)(inb + (((size_t)iy_*2 + (t_&1))*IPWH + axb[f_] + (t_>>1))*IC + ico_); \
    }                                                                            \
  } while(0)

#define MFMAC(Ax, Bx) do {                                                       \
    _Pragma("unroll") for (int f_ = 0; f_ < WM; f_++)                            \
      _Pragma("unroll") for (int n_ = 0; n_ < WN; n_++)                          \
        acc[f_][n_] = __builtin_amdgcn_mfma_f32_16x16x32_bf16(Ax[f_], Bx[n_], acc[f_][n_], 0, 0, 0); \
  } while(0)

template <int IC, int OC, int KSZ, int S, int P, int CPR, int NCH,
          int IPH, int IPW, int OWL, int OPH, int OPW,
          int WM, int WN, int WVM, int WVN, bool PERS>
__global__ __launch_bounds__(WVM*WVN*64) void conv_mfma(
    const u16* __restrict__ in, const u16* __restrict__ wmfma,
    const float* __restrict__ bias, u16* __restrict__ out,
    float2* __restrict__ part2) {
  constexpr int OW = 1 << OWL;
  constexpr int PADOFF = 2 - P;
  constexpr int IPWH = IPW / 2;
  constexpr int OPWH = OPW / 2;
  const int tid = threadIdx.x, lane = tid & 63;
  const int w = tid >> 6, wm = w % WVM, wn = w / WVM;
  const int l15 = lane & 15, sub = lane >> 4;
  const int b = blockIdx.z;
  const int px0 = blockIdx.x * (16*WM*WVM) + wm * (16*WM);
  const int oc0 = blockIdx.y * (16*WN*WVN) + wn * (16*WN);

  int oyf[WM], oxb[WM], axb[WM];
#pragma unroll
  for (int f = 0; f < WM; f++) {
    int p = px0 + f*16;
    oyf[f] = p >> OWL;
    oxb[f] = p & (OW-1);
    axb[f] = oxb[f] + l15;
  }
  const u16* inb = in + (size_t)b*IPH*IPW*IC;
  const u16* wbase = wmfma + (PERS ? (size_t)b*NCH*OC*32 : (size_t)0);

  float4v acc[WM][WN];
#pragma unroll
  for (int f = 0; f < WM; f++)
#pragma unroll
    for (int n = 0; n < WN; n++) acc[f][n] = (float4v){0.f,0.f,0.f,0.f};

  constexpr int NC = KSZ * CPR;
  short8v A0[WM], B0[WN], A1[WM], B1[WN];
  LOADC(0, A0, B0);
#pragma unroll
  for (int c = 0; c < NC; c += 2) {
    if (c + 1 < NC) LOADC(c + 1, A1, B1);
    MFMAC(A0, B0);
    if (c + 2 < NC) LOADC(c + 2, A0, B0);
    if (c + 1 < NC) MFMAC(A1, B1);
  }

  // epilogue: +bias, store bf16 interior (parity layout), BN partials
  float s[WN], q[WN];
#pragma unroll
  for (int n = 0; n < WN; n++) { s[n] = 0.f; q[n] = 0.f; }
#pragma unroll
  for (int f = 0; f < WM; f++) {
    const int oxs = oxb[f] + sub*4;
    const size_t rowb2 = ((size_t)b*OPH + oyf[f] + 2)*2;
#pragma unroll
    for (int n = 0; n < WN; n++) {
      int oc = oc0 + n*16 + l15;
      float bv = bias[oc];
#pragma unroll
      for (int rr = 0; rr < 4; rr++) {
        float v = acc[f][n][rr] + bv;
        int x_out = oxs + rr + 2;
        out[((rowb2 + (x_out & 1))*OPWH + (x_out >> 1))*OC + oc] = f2bf(v);
        s[n] += v; q[n] += v*v;
      }
    }
  }
#pragma unroll
  for (int n = 0; n < WN; n++) {
    s[n] += __shfl_xor(s[n], 16); s[n] += __shfl_xor(s[n], 32);
    q[n] += __shfl_xor(q[n], 16); q[n] += __shfl_xor(q[n], 32);
  }
  __shared__ float sred[WVM*WVN][WN][16][2];
  if (sub == 0) {
#pragma unroll
    for (int n = 0; n < WN; n++) { sred[w][n][l15][0] = s[n]; sred[w][n][l15][1] = q[n]; }
  }
  __syncthreads();
  const int NBp = gridDim.x * gridDim.z;
  const int pb = blockIdx.z * gridDim.x + blockIdx.x;
  const int tot = WVN*WN*16;
  if (tid < tot) {
    int c16 = tid & 15, n = (tid >> 4) % WN, wn2 = tid / (16*WN);
    float S_ = 0.f, Q_ = 0.f;
    for (int wm2 = 0; wm2 < WVM; wm2++) {
      S_ += sred[wn2*WVM + wm2][n][c16][0];
      Q_ += sred[wn2*WVM + wm2][n][c16][1];
    }
    int c = blockIdx.y*(16*WN*WVN) + wn2*(16*WN) + n*16 + c16;
    part2[(size_t)c*NBp + pb] = make_float2(S_, Q_);
  }
}

// ---------------------------------------------------------------------------
// BN stage2: reduce per-block partials -> (scale, shift)
// ---------------------------------------------------------------------------
__global__ void bn_stage2(const float2* __restrict__ part2, const float* __restrict__ g,
                          const float* __restrict__ bb, float* __restrict__ stats,
                          int NBp, float invN) {
  int c = blockIdx.x;
  float s = 0.f, q = 0.f;
  for (int i = threadIdx.x; i < NBp; i += 64) {
    float2 p = part2[(size_t)c*NBp + i];
    s += p.x; q += p.y;
  }
  for (int o = 32; o > 0; o >>= 1) { s += __shfl_down(s, o); q += __shfl_down(q, o); }
  if (threadIdx.x == 0) {
    float m = s * invN;
    float var = q * invN - m*m;
    float sc = g[c] * rsqrtf(var + BN_EPS);
    stats[2*c] = sc;
    stats[2*c+1] = bb[c] - m*sc;
  }
}

// bn finalize in place over PARITY-SPLIT padded buffer.
template <int C, int PH, int PW, int HH, int WW>
__global__ __launch_bounds__(256) void bn_fin(u16* __restrict__ y, const float* __restrict__ stats,
                                              int total8) {
  int i = blockIdx.x*256 + threadIdx.x;
  if (i >= total8) return;
  size_t e = (size_t)i*8;
  int c0 = (int)(e & (C-1));
  int px = (int)(e / C);
  int xp = px % (PW/2);
  int t2 = px / (PW/2);
  int yy = (t2 >> 1) % PH;
  bool interior = (yy >= 2) & (yy < 2+HH) & (xp >= 1) & (xp <= WW/2);
  short8v u = *(short8v*)(y + e);
  short8v o;
#pragma unroll
  for (int j = 0; j < 8; j++) {
    float v = bf2f((u16)u[j]) * stats[2*(c0+j)] + stats[2*(c0+j)+1];
    o[j] = interior ? (short)f2bf(lrelu(v)) : (short)0;
  }
  *(short8v*)(y + e) = o;
}

// final: lrelu(bn(y6pad interior)) parity NHWC bf16 -> NCHW fp32 d_out
__global__ __launch_bounds__(256) void out_k(const u16* __restrict__ y6,
                                             const float* __restrict__ stats,
                                             float* __restrict__ out) {
  int i = blockIdx.x*256 + threadIdx.x;
  if (i >= 131072) return;
  size_t e = (size_t)i*4;
  int c0 = (int)(e & 127);
  int px = (int)(e >> 7);
  int loc = px & 255, b = px >> 8;
  int y = loc >> 4, x = loc & 15;
  int xi = x + 2;
  const u16* src = y6 + ((((size_t)b*20 + y + 2)*2 + (xi & 1))*10 + (xi >> 1))*128 + c0;
  ushort4 u = *(const ushort4*)src;
  float vv[4] = {bf2f(u.x), bf2f(u.y), bf2f(u.z), bf2f(u.w)};
#pragma unroll
  for (int j = 0; j < 4; j++) {
    int c = c0 + j;
    float v = vv[j] * stats[2*c] + stats[2*c+1];
    out[(((size_t)b*128 + c) << 8) + loc] = lrelu(v);
  }
}

// ---------------------------------------------------------------------------
extern "C" void kernel_launch(void* const* d_in, const int* in_sizes, int n_in,
                              void* d_out, int out_size, void* d_ws, size_t ws_size,
                              hipStream_t stream) {
  const float* x    = (const float*)d_in[0];
  const float* cw   = (const float*)d_in[1];
  const float* w11  = (const float*)d_in[2];
  const float* b11  = (const float*)d_in[3];
  const float* w12  = (const float*)d_in[4];
  const float* b12  = (const float*)d_in[5];
  const float* bn1g = (const float*)d_in[6];
  const float* bn1b = (const float*)d_in[7];
  const float* c2w[4] = {(const float*)d_in[8], (const float*)d_in[12],
                         (const float*)d_in[16], (const float*)d_in[20]};
  const float* c2b[4] = {(const float*)d_in[9], (const float*)d_in[13],
                         (const float*)d_in[17], (const float*)d_in[21]};
  const float* bng[4] = {(const float*)d_in[10], (const float*)d_in[14],
                         (const float*)d_in[18], (const float*)d_in[22]};
  const float* bnb[4] = {(const float*)d_in[11], (const float*)d_in[15],
                         (const float*)d_in[19], (const float*)d_in[23]};

  char* ws = (char*)d_ws;
  u16* y3   = (u16*)(ws);                          // 16x132x2x66x32 = 17,842,176
  u16* y4   = (u16*)(ws + 17842176);               // 16x68x2x34x64  =  9,469,952
  u16* y5   = (u16*)(ws + 27312128);               // 16x36x2x18x128 =  5,308,416
  u16* y6   = (u16*)(ws + 32620544);               // 16x20x2x10x128 =  1,638,400
  u16* yT2  = (u16*)(ws + 68158464);               // 16x260x2x130x16 = 34,611,200
  u16* wl2m = (u16*)(ws + 102769664);              // 163,840
  float* bl2    = (float*)(ws + 102933504);        // 64
  float2* part2 = (float2*)(ws + 102933568);       // 524,288
  float* stats2 = (float*)(ws + 103457856);
  float* stats3 = stats2 + 32;
  float* stats4 = stats3 + 64;
  float* stats5 = stats4 + 128;
  float* stats6 = stats5 + 256;
  u16* wl1d = (u16*)(ws + 103460800);              // 98,304
  u16* wS1  = (u16*)(ws + 103559104);              // 30,720
  u16* wS2  = (u16*)(ws + 103589824);              // 102,400
  u16* wS3  = (u16*)(ws + 103692224);              // 147,456
  u16* wS4  = (u16*)(ws + 103839680);              // 294,912 -> ends 104,134,592

  prep_all<<<1637, 256, 0, stream>>>(w11, w12, b12, cw,
                                     c2w[0], c2w[1], c2w[2], c2w[3],
                                     wl1d, wl2m, bl2, wS1, wS2, wS3, wS4);

  // FUSED L1+L2: x -> yT2pad (pre-BN) + partials. h1 never touches HBM.
  conv_l12<<<dim3(128, 1, 16), 512, 0, stream>>>(x, wl1d, b11, wl2m, bl2, yT2, part2);

  bn_stage2<<<16, 64, 0, stream>>>(part2, bn1g, bn1b, stats2, 2048, 1.f/1048576.f);
  bn_fin<16,260,260,256,256><<<8450, 256, 0, stream>>>(yT2, stats2, 2163200);

  // S1: 16->32 k5 s2 -> y3pad
  conv_mfma<16,32,5,2,2, 3,15, 260,260, 7, 132,132, 2,2,4,1, false>
      <<<dim3(128,1,16), 256, 0, stream>>>(yT2, wS1, c2b[0], y3, part2);
  bn_stage2<<<32, 64, 0, stream>>>(part2, bng[0], bnb[0], stats3, 2048, 1.f/262144.f);
  bn_fin<32,132,132,128,128><<<4356, 256, 0, stream>>>(y3, stats3, 1115136);

  // S2: 32->64 k5 s2 -> y4pad
  conv_mfma<32,64,5,2,2, 5,25, 132,132, 6, 68,68, 2,2,2,2, false>
      <<<dim3(64,1,16), 256, 0, stream>>>(y3, wS2, c2b[1], y4, part2);
  bn_stage2<<<64, 64, 0, stream>>>(part2, bng[1], bnb[1], stats4, 1024, 1.f/65536.f);
  bn_fin<64,68,68,64,64><<<2312, 256, 0, stream>>>(y4, stats4, 591872);

  // S3: 64->128 k3 s2 -> y5pad
  conv_mfma<64,128,3,2,1, 6,18, 68,68, 5, 36,36, 2,2,2,2, false>
      <<<dim3(16,2,16), 256, 0, stream>>>(y4, wS3, c2b[2], y5, part2);
  bn_stage2<<<128, 64, 0, stream>>>(part2, bng[2], bnb[2], stats5, 256, 1.f/16384.f);
  bn_fin<128,36,36,32,32><<<1296, 256, 0, stream>>>(y5, stats5, 331776);

  // S4: 128->128 k3 s2 -> y6pad (pre-BN)
  conv_mfma<128,128,3,2,1, 12,36, 36,36, 4, 20,20, 2,2,1,2, false>
      <<<dim3(8,2,16), 128, 0, stream>>>(y5, wS4, c2b[3], y6, part2);
  bn_stage2<<<128, 64, 0, stream>>>(part2, bng[3], bnb[3], stats6, 128, 1.f/4096.f);

  out_k<<<512, 256, 0, stream>>>(y6, stats6, (float*)d_out);
}